// Round 1
// baseline (815.614 us; speedup 1.0000x reference)
//
#include <hip/hip_runtime.h>

typedef unsigned short u16;
typedef __attribute__((ext_vector_type(8))) short short8;
typedef __attribute__((ext_vector_type(8))) unsigned short ushort8;
typedef __attribute__((ext_vector_type(4))) unsigned short ushort4v;
typedef __attribute__((ext_vector_type(4))) float f32x4;

#define NB 4
#define SS 4096
#define DD 1024

__device__ __forceinline__ u16 f2bf(float x) {
  unsigned u = __builtin_bit_cast(unsigned, x);
  u = (u + 0x7FFFu + ((u >> 16) & 1u)) >> 16;
  return (u16)u;
}
__device__ __forceinline__ float bf2f(u16 b) {
  unsigned u = ((unsigned)b) << 16;
  return __builtin_bit_cast(float, u);
}
__device__ __forceinline__ void gload16(const void* g, void* l) {
  __builtin_amdgcn_global_load_lds((const __attribute__((address_space(1))) void*)g,
                                   (__attribute__((address_space(3))) void*)l, 16, 0, 0);
}

// ---------------- kernel 1: logits (f32), loss partials, pred, h->bf16 -----
__global__ __launch_bounds__(256) void k_logits(
    const float* __restrict__ h, const int* __restrict__ lab,
    const float* __restrict__ Wl, const float* __restrict__ bl,
    u16* __restrict__ h16, int* __restrict__ pred, float* __restrict__ lossPart)
{
  const int t = threadIdx.x, w = t >> 6, lane = t & 63;
  const int tok = blockIdx.x * 4 + w;
  const float4* h4p = (const float4*)(h + (size_t)tok * DD);
  const float4* wl4 = (const float4*)Wl;  // Wl row d = one float4
  float p0 = 0.f, p1 = 0.f, p2 = 0.f, p3 = 0.f;
#pragma unroll
  for (int i = 0; i < 4; ++i) {
    const int d = i * 256 + lane * 4;
    float4 hv = h4p[i * 64 + lane];
    ushort4v hb;
    hb[0] = f2bf(hv.x); hb[1] = f2bf(hv.y); hb[2] = f2bf(hv.z); hb[3] = f2bf(hv.w);
    *(ushort4v*)(h16 + (size_t)tok * DD + d) = hb;
    float4 w0 = wl4[d], w1 = wl4[d + 1], w2 = wl4[d + 2], w3 = wl4[d + 3];
    p0 += hv.x * w0.x + hv.y * w1.x + hv.z * w2.x + hv.w * w3.x;
    p1 += hv.x * w0.y + hv.y * w1.y + hv.z * w2.y + hv.w * w3.y;
    p2 += hv.x * w0.z + hv.y * w1.z + hv.z * w2.z + hv.w * w3.z;
    p3 += hv.x * w0.w + hv.y * w1.w + hv.z * w2.w + hv.w * w3.w;
  }
#pragma unroll
  for (int m = 32; m; m >>= 1) {
    p0 += __shfl_xor(p0, m); p1 += __shfl_xor(p1, m);
    p2 += __shfl_xor(p2, m); p3 += __shfl_xor(p3, m);
  }
  __shared__ float ls[4];
  if (lane == 0) {
    float l[4] = {p0 + bl[0], p1 + bl[1], p2 + bl[2], p3 + bl[3]};
    int bi = 0; float bv = l[0];
#pragma unroll
    for (int c = 1; c < 4; ++c) if (l[c] > bv) { bv = l[c]; bi = c; }  // first-max like np.argmax
    pred[tok] = bi;
    float se = 0.f;
#pragma unroll
    for (int c = 0; c < 4; ++c) se += expf(l[c] - bv);
    float lse = bv + logf(se);
    ls[w] = lse - l[lab[tok]];
  }
  __syncthreads();
  if (t == 0) lossPart[blockIdx.x] = ls[0] + ls[1] + ls[2] + ls[3];
}

// ---------------- kernel 2: weights -> transposed bf16 ---------------------
__global__ __launch_bounds__(256) void k_wconv(
    const float* __restrict__ W0, const float* __restrict__ W1,
    const float* __restrict__ W2, const float* __restrict__ W3,
    u16* __restrict__ Wt)
{
  const int gid = blockIdx.x * 256 + threadIdx.x;
  const int mat = gid >> 20;
  const int rem = gid & ((1 << 20) - 1);
  const int n = rem >> 10, k = rem & 1023;
  const float* W = (mat == 0) ? W0 : (mat == 1) ? W1 : (mat == 2) ? W2 : W3;
  Wt[((size_t)mat << 20) + (size_t)n * 1024 + k] = f2bf(W[(size_t)k * 1024 + n]);
}

// ---------------- kernel 3: BIOS chunk scan (1 block / batch) --------------
__global__ __launch_bounds__(256) void k_scan(
    const int* __restrict__ pred, int* __restrict__ cstart, int* __restrict__ ccnt)
{
  const int b = blockIdx.x, t = threadIdx.x;
  const int4* p4 = (const int4*)(pred + (size_t)b * SS);
  int labv[16];
#pragma unroll
  for (int i = 0; i < 4; ++i) {
    int4 v = p4[t * 4 + i];
    labv[i * 4 + 0] = v.x; labv[i * 4 + 1] = v.y;
    labv[i * 4 + 2] = v.z; labv[i * 4 + 3] = v.w;
  }
  // transfer fn ext' = a | (b & ext): compose over the thread's 16 tokens
  int A = 0, Bc = 1;
#pragma unroll
  for (int e = 0; e < 16; ++e) {
    int a = (labv[e] == 0), bb = (labv[e] == 1);
    A = a | (bb & A);
    Bc = bb & Bc;
  }
  __shared__ int sA[256], sB[256], sC[256];
  sA[t] = A; sB[t] = Bc;
  __syncthreads();
  for (int off = 1; off < 256; off <<= 1) {  // inclusive Hillis-Steele
    int pa = 0, pb = 1;
    if (t >= off) { pa = sA[t - off]; pb = sB[t - off]; }
    __syncthreads();
    A = A | (Bc & pa); Bc = Bc & pb;
    sA[t] = A; sB[t] = Bc;
    __syncthreads();
  }
  const int extIn = (t == 0) ? 0 : sA[t - 1];
  int ext = extIn, nst = 0;
#pragma unroll
  for (int e = 0; e < 16; ++e) {
    int cont = (labv[e] == 1) & ext;
    nst += !cont;
    ext = (labv[e] == 0) | cont;
  }
  sC[t] = nst;
  __syncthreads();
  int tot = nst;
  for (int off = 1; off < 256; off <<= 1) {
    int pc = 0;
    if (t >= off) pc = sC[t - off];
    __syncthreads();
    tot += pc;
    sC[t] = tot;
    __syncthreads();
  }
  const int base = tot - nst;
  const int total = sC[255];
  if (t == 0) { ccnt[b] = total; cstart[b * (SS + 1) + total] = SS; }  // sentinel
  ext = extIn; int id = base;
#pragma unroll
  for (int e = 0; e < 16; ++e) {
    int cont = (labv[e] == 1) & ext;
    if (!cont) cstart[b * (SS + 1) + id++] = t * 16 + e;
    ext = (labv[e] == 0) | cont;
  }
}

// ---------------- kernel 4: segment-mean pooling (1 wave / chunk) ----------
__global__ __launch_bounds__(256) void k_pool(
    const float* __restrict__ h, const int* __restrict__ cstart,
    const int* __restrict__ ccnt, u16* __restrict__ cemb)
{
  const int t = threadIdx.x, w = t >> 6, lane = t & 63;
  const int gw = blockIdx.x * 4 + w;
  const int b = gw >> 12, c = gw & (SS - 1);
  u16* out = cemb + (size_t)gw * DD + lane * 16;
  if (c >= ccnt[b]) {
    ushort8 z = {0, 0, 0, 0, 0, 0, 0, 0};
    *(ushort8*)out = z; *(ushort8*)(out + 8) = z;
    return;
  }
  const int s0 = cstart[b * (SS + 1) + c], s1 = cstart[b * (SS + 1) + c + 1];
  float acc[16] = {};
  for (int s = s0; s < s1; ++s) {
    const float4* hp = (const float4*)(h + ((size_t)b * SS + s) * DD + lane * 16);
#pragma unroll
    for (int ii = 0; ii < 4; ++ii) {
      float4 v = hp[ii];
      acc[ii * 4 + 0] += v.x; acc[ii * 4 + 1] += v.y;
      acc[ii * 4 + 2] += v.z; acc[ii * 4 + 3] += v.w;
    }
  }
  const float inv = 1.f / (float)(s1 - s0);
  ushort8 o0, o1;
#pragma unroll
  for (int e = 0; e < 8; ++e) { o0[e] = f2bf(acc[e] * inv); o1[e] = f2bf(acc[8 + e] * inv); }
  *(ushort8*)out = o0; *(ushort8*)(out + 8) = o1;
}

// ---------------- NT bf16 GEMM: C[m,n] = scale*sum_k A[m,k]*Bt[n,k] + bias[n]
// 128x128 tile, BK=64, 4 waves, global_load_lds w=16, 16x16x32 MFMA (m97 structure)
template <int OUTF32>
__global__ __launch_bounds__(256) void gemm_nt(
    const u16* __restrict__ A, const u16* __restrict__ Bt, void* __restrict__ Cp,
    const float* __restrict__ bias, float scale, int M, int N, int K)
{
  __shared__ u16 lsA[128 * 64], lsB[128 * 64];
  const int t = threadIdx.x, lane = t & 63, w = t >> 6;
  const int wr = w >> 1, wc = w & 1;
  const int m0 = blockIdx.y * 128, n0 = blockIdx.x * 128;
  const f32x4 zero = {0.f, 0.f, 0.f, 0.f};
  f32x4 acc[4][4];
#pragma unroll
  for (int i = 0; i < 4; ++i)
#pragma unroll
    for (int j = 0; j < 4; ++j) acc[i][j] = zero;

  const u16* Ag = A + (size_t)(m0 + (t >> 3)) * K + (t & 7) * 8;
  const u16* Bg = Bt + (size_t)(n0 + (t >> 3)) * K + (t & 7) * 8;
  u16* lA = lsA + t * 8;  // byte off t*16 = wave-uniform base + lane*16
  u16* lB = lsB + t * 8;

  for (int kt = 0; kt < K; kt += 64) {
#pragma unroll
    for (int p = 0; p < 4; ++p) {
      gload16(Ag + (size_t)(p * 32) * K + kt, lA + p * 2048);
      gload16(Bg + (size_t)(p * 32) * K + kt, lB + p * 2048);
    }
    __syncthreads();  // compiler emits vmcnt(0) drain before barrier
#pragma unroll
    for (int kk = 0; kk < 2; ++kk) {
      short8 af[4], bfv[4];
      const int lrow = lane & 15, lk = kk * 32 + (lane >> 4) * 8;
#pragma unroll
      for (int i = 0; i < 4; ++i)
        af[i] = *(const short8*)(lsA + (wr * 64 + i * 16 + lrow) * 64 + lk);
#pragma unroll
      for (int j = 0; j < 4; ++j)
        bfv[j] = *(const short8*)(lsB + (wc * 64 + j * 16 + lrow) * 64 + lk);
#pragma unroll
      for (int i = 0; i < 4; ++i)
#pragma unroll
        for (int j = 0; j < 4; ++j)
          asm volatile("v_mfma_f32_16x16x32_bf16 %0, %1, %2, %0"
                       : "+v"(acc[i][j]) : "v"(af[i]), "v"(bfv[j]));
    }
    __syncthreads();
  }
  // epilogue: C/D layout col=lane&15, row=(lane>>4)*4+q
  const int colb = n0 + wc * 64 + (lane & 15);
  const int rowb = m0 + wr * 64 + (lane >> 4) * 4;
#pragma unroll
  for (int j = 0; j < 4; ++j) {
    const int col = colb + j * 16;
    const float bv = bias ? bias[col] : 0.f;
#pragma unroll
    for (int i = 0; i < 4; ++i) {
#pragma unroll
      for (int q = 0; q < 4; ++q) {
        const float v = acc[i][j][q] * scale + bv;
        const size_t idx = (size_t)(rowb + i * 16 + q) * N + col;
        if (OUTF32) ((float*)Cp)[idx] = v;
        else        ((u16*)Cp)[idx]  = f2bf(v);
      }
    }
  }
}

// ---------------- masked row softmax, bf16 in-place -------------------------
__global__ __launch_bounds__(256) void k_softmax(
    u16* __restrict__ sc, const int* __restrict__ ccnt, int b)
{
  const int t = threadIdx.x, lane = t & 63, w = t >> 6;
  const int row = blockIdx.x;
  const int Cb = ccnt[b];
  u16* p = sc + (size_t)row * SS + t * 16;
  ushort8 v0 = *(ushort8*)p, v1 = *(ushort8*)(p + 8);
  float x[16];
#pragma unroll
  for (int e = 0; e < 8; ++e) { x[e] = bf2f(v0[e]); x[8 + e] = bf2f(v1[e]); }
  const int cb0 = t * 16;
  float m = -1e30f;
#pragma unroll
  for (int e = 0; e < 16; ++e) if (cb0 + e < Cb) m = fmaxf(m, x[e]);
#pragma unroll
  for (int off = 32; off; off >>= 1) m = fmaxf(m, __shfl_xor(m, off));
  __shared__ float red[4], red2[4];
  if (lane == 0) red[w] = m;
  __syncthreads();
  m = fmaxf(fmaxf(red[0], red[1]), fmaxf(red[2], red[3]));
  float ssum = 0.f;
#pragma unroll
  for (int e = 0; e < 16; ++e) {
    float ev = (cb0 + e < Cb) ? __expf(x[e] - m) : 0.f;
    x[e] = ev; ssum += ev;
  }
#pragma unroll
  for (int off = 32; off; off >>= 1) ssum += __shfl_xor(ssum, off);
  if (lane == 0) red2[w] = ssum;
  __syncthreads();
  ssum = red2[0] + red2[1] + red2[2] + red2[3];
  const float inv = 1.f / ssum;
#pragma unroll
  for (int e = 0; e < 8; ++e) { v0[e] = f2bf(x[e] * inv); v1[e] = f2bf(x[8 + e] * inv); }
  *(ushort8*)p = v0; *(ushort8*)(p + 8) = v1;
}

// ---------------- bf16 transpose v[b][c][d] -> vT[b][d][c] ------------------
__global__ __launch_bounds__(256) void k_transpose(
    const u16* __restrict__ v, u16* __restrict__ vt)
{
  __shared__ u16 ts[64][80];  // row stride 160B keeps 16B alignment
  const int t = threadIdx.x;
  const int d0 = blockIdx.x * 64, c0 = blockIdx.y * 64, b = blockIdx.z;
#pragma unroll
  for (int p = 0; p < 2; ++p) {
    const int idx = p * 256 + t, r = idx >> 3, cc = idx & 7;
    ushort8 val = *(const ushort8*)(v + ((size_t)b * SS + c0 + r) * DD + d0 + cc * 8);
    *(ushort8*)&ts[r][cc * 8] = val;
  }
  __syncthreads();
#pragma unroll
  for (int p = 0; p < 2; ++p) {
    const int idx = p * 256 + t, r = idx >> 3, cc = idx & 7;
    ushort8 o;
#pragma unroll
    for (int e = 0; e < 8; ++e) o[e] = ts[cc * 8 + e][r];
    *(ushort8*)(vt + ((size_t)b * DD + d0 + r) * SS + c0 + cc * 8) = o;
  }
}

// ---------------- loss finalize ---------------------------------------------
__global__ __launch_bounds__(256) void k_lossfin(
    const float* __restrict__ part, float* __restrict__ out)
{
  const int t = threadIdx.x, lane = t & 63, w = t >> 6;
  float s = 0.f;
  for (int i = t; i < 4096; i += 256) s += part[i];
#pragma unroll
  for (int off = 32; off; off >>= 1) s += __shfl_xor(s, off);
  __shared__ float r[4];
  if (lane == 0) r[w] = s;
  __syncthreads();
  if (t == 0) out[0] = (r[0] + r[1] + r[2] + r[3]) * (1.f / (NB * SS));
}

extern "C" void kernel_launch(void* const* d_in, const int* in_sizes, int n_in,
                              void* d_out, int out_size, void* d_ws, size_t ws_size,
                              hipStream_t stream) {
  const float* h  = (const float*)d_in[0];
  const int* plab = (const int*)d_in[1];
  const float* Wl = (const float*)d_in[2];
  const float* bl = (const float*)d_in[3];
  const float* Wq = (const float*)d_in[4];
  const float* bq = (const float*)d_in[5];
  const float* Wk = (const float*)d_in[6];
  const float* bk = (const float*)d_in[7];
  const float* Wv = (const float*)d_in[8];
  const float* bv = (const float*)d_in[9];
  const float* Wo = (const float*)d_in[10];
  const float* bo = (const float*)d_in[11];
  float* out = (float*)d_out;

  char* ws = (char*)d_ws;
  const size_t SZ = (size_t)NB * SS * DD * 2;  // 32 MB (bf16 [B*S, D])
  u16* h16      = (u16*)(ws + 0 * SZ);  // dead after q GEMM -> aliases scores
  u16* cemb     = (u16*)(ws + 1 * SZ);  // dead after k,v GEMM -> aliases attended
  u16* q        = (u16*)(ws + 2 * SZ);
  u16* kk       = (u16*)(ws + 3 * SZ);
  u16* vv       = (u16*)(ws + 4 * SZ);
  u16* vt       = (u16*)(ws + 5 * SZ);
  u16* Wt       = (u16*)(ws + 6 * SZ);                     // 4 x 1024x1024 bf16 = 8 MB
  char* ws2     = ws + 6 * SZ + (size_t)4 * 1024 * 1024 * 2;
  int* pred     = (int*)ws2;                               // 64 KB
  int* cstart   = (int*)(ws2 + 65536);                     // 4*(S+1) ints
  int* ccnt     = (int*)(ws2 + 65536 + 4 * (SS + 1) * 4);
  float* lossPart = (float*)(ws2 + 65536 + 4 * (SS + 1) * 4 + 64);
  u16* scores   = h16;   // per-batch [S,S] bf16 = 32 MB, alias (q GEMM completes first)
  u16* attended = cemb;  // [B*S, D] bf16, alias (k,v GEMMs complete first)

  k_logits<<<dim3(NB * SS / 4), 256, 0, stream>>>(h, plab, Wl, bl, h16, pred, lossPart);
  k_wconv<<<dim3(4 * 1024 * 1024 / 256), 256, 0, stream>>>(Wq, Wk, Wv, Wo, Wt);
  k_scan<<<dim3(NB), 256, 0, stream>>>(pred, cstart, ccnt);
  k_pool<<<dim3(NB * SS / 4), 256, 0, stream>>>(h, cstart, ccnt, cemb);

  gemm_nt<0><<<dim3(DD / 128, NB * SS / 128), 256, 0, stream>>>(
      h16, Wt, q, bq, 1.f, NB * SS, DD, DD);
  gemm_nt<0><<<dim3(DD / 128, NB * SS / 128), 256, 0, stream>>>(
      cemb, Wt + (1 << 20), kk, bk, 1.f, NB * SS, DD, DD);
  gemm_nt<0><<<dim3(DD / 128, NB * SS / 128), 256, 0, stream>>>(
      cemb, Wt + 2 * (1 << 20), vv, bv, 1.f, NB * SS, DD, DD);
  k_transpose<<<dim3(DD / 64, SS / 64, NB), 256, 0, stream>>>(vv, vt);

  const float scl = 1.f / 32.f;  // 1/sqrt(DC)
  for (int b = 0; b < NB; ++b) {
    gemm_nt<0><<<dim3(SS / 128, SS / 128), 256, 0, stream>>>(
        q + (size_t)b * SS * DD, kk + (size_t)b * SS * DD, scores, nullptr, scl, SS, SS, DD);
    k_softmax<<<dim3(SS), 256, 0, stream>>>(scores, ccnt, b);
    gemm_nt<0><<<dim3(DD / 128, SS / 128), 256, 0, stream>>>(
        scores, vt + (size_t)b * DD * SS, attended + (size_t)b * SS * DD, nullptr, 1.f, SS, DD, SS);
  }
  gemm_nt<1><<<dim3(DD / 128, NB * SS / 128), 256, 0, stream>>>(
      attended, Wt + 3 * (1 << 20), out, bo, 1.f, NB * SS, DD, DD);
  k_lossfin<<<dim3(1), 256, 0, stream>>>(lossPart, out + (size_t)NB * SS * DD);
}